// Round 19
// baseline (28.369 us; speedup 1.0000x reference)
//
#include <hip/hip_runtime.h>

// StructOnlyClassifier R19: R18 + full load/consume phase split.
//  - ALL 10 quad loads (both segments) issue back-to-back into t[2][5] before
//    any consumption -> 2x VMEM in flight per wave (head/tail scalars and the
//    fallback loop no longer fence segment B's loads behind segment A's use).
//  - per-element interval predication (idx in [s,e)) from floor4(s): head/tail
//    scalar loads deleted; clamp stays segment-local (R16 traffic fix).
// Reduce + MLP identical to R18 (packed u64 reduce, LDS float4 layer-2).

constexpr int GPW = 2;     // graphs per wave
constexpr int GPB = 8;     // graphs per block (4 waves)
constexpr int UNR = 5;     // 5*64 quads = 1280 nodes per graph before fallback

__device__ __forceinline__ int interp_lower_bound(
    const int* __restrict__ batch, int n, int stride, int g)
{
    // first idx with batch[idx] >= g. Invariant: lb in [blo, bhi], 4-aligned.
    int blo = 0, bhi = n;
    long long pos = (long long)g * stride - (stride >> 1);
    int it = 0;
    while (bhi - blo > 4) {
        int p;
        if (it < 5) {                         // interpolation phase
            long long pc = pos;
            if (pc < blo) pc = blo;
            if (pc > bhi - 4) pc = bhi - 4;
            p = (int)pc & ~3;
            ++it;
        } else {                              // binary fallback
            p = ((blo + bhi) >> 1) & ~3;
            if (p > bhi - 4) p = bhi - 4;
        }
        const int4 q = *(const int4*)(batch + p);
        if (q.w < g) {
            blo = p + 4;
            pos = p + 4 + (long long)(g - q.w) * stride - (stride >> 1);
        } else if (q.x >= g) {
            bhi = p;
            pos = p + (long long)(g - q.x) * stride - (stride >> 1);
        } else {
            return p + 1 + (q.y < g) + (q.z < g);
        }
    }
    if (bhi > blo) {
        const int4 q = *(const int4*)(batch + blo);
        return blo + (q.x < g) + (q.y < g) + (q.z < g) + (q.w < g);
    }
    return blo;
}

__global__ __launch_bounds__(256) void fused_kernel(
    const int* __restrict__ batch, const int* __restrict__ ntype,
    const float* __restrict__ W1, const float* __restrict__ b1,
    const float* __restrict__ W2, const float* __restrict__ b2,
    const float* __restrict__ W3, const float* __restrict__ b3,
    float* __restrict__ out, int n, int B, int stride)
{
    __shared__ float sW1[128], sb1[32], sb2[16], sW3[16], sb3v[1];
    __shared__ __attribute__((aligned(16))) float sW2T[16 * 36]; // [m][j] pad 36
    __shared__ __attribute__((aligned(16))) float sh1[4][2][32]; // [wave][half][j]
    __shared__ int sS[GPB + 1];

    const int tid = threadIdx.x;
    const int bi  = blockIdx.x;

    // ---- weight staging (issue loads first) ----
    if (tid < 128) sW1[tid] = W1[tid];
    for (int i = tid; i < 512; i += 256) {            // transpose W2 (32,16)
        const int j = i >> 4, m = i & 15;
        sW2T[m * 36 + j] = W2[i];
    }
    if      (tid < 32)  sb1[tid]      = b1[tid];
    else if (tid < 48)  sb2[tid - 32] = b2[tid - 32];
    else if (tid < 64)  sW3[tid - 48] = W3[tid - 48];
    else if (tid == 64) sb3v[0]       = b3[0];

    // ---- block-shared boundary searches: 9 per block ----
    if (tid <= GPB) {
        const int g = bi * GPB + tid;                 // <= B by construction
        sS[tid] = interp_lower_bound(batch, n, stride, g);
    }
    __syncthreads();

    const int w    = tid >> 6;
    const int lane = tid & 63;
    const int g0   = bi * GPB + w * GPW;

    const int sA = sS[w * GPW];
    const int sB = sS[w * GPW + 1];
    const int sC = sS[w * GPW + 2];

    const int4* nt4 = (const int4*)ntype;

    // ---- LOAD PHASE: all 10 quad loads issue back-to-back ----
    int4 t[2][UNR];
    int qa[2];
    #pragma unroll
    for (int i = 0; i < 2; ++i) {
        const int s_ = (i == 0) ? sA : sB;
        const int e_ = (i == 0) ? sB : sC;
        const int q0    = (s_ >> 2) + lane;
        const int qlast = max((e_ - 1) >> 2, 0);      // segment-local clamp
        qa[i] = q0;
        #pragma unroll
        for (int u = 0; u < UNR; ++u)
            t[i][u] = nt4[min(q0 + u * 64, qlast)];
    }

    // ---- CONSUME PHASE: per-element interval predication ----
    unsigned long long pk = 0ull;    // [0:16)=sA [16:32)=oA [32:48)=sB [48:64)=oB
    #pragma unroll
    for (int i = 0; i < 2; ++i) {
        const int s_ = (i == 0) ? sA : sB;
        const int e_ = (i == 0) ? sB : sC;
        int ssum = 0, osum = 0;
        #pragma unroll
        for (int u = 0; u < UNR; ++u) {
            const int base = (qa[i] + u * 64) << 2;   // unclamped element base
            const int4 v = t[i][u];
            // element idx = base+c active iff s_ <= idx < e_
            const int ax = (base + 0 >= s_) & (base + 0 < e_) ? v.x : 0;
            const int ay = (base + 1 >= s_) & (base + 1 < e_) ? v.y : 0;
            const int az = (base + 2 >= s_) & (base + 2 < e_) ? v.z : 0;
            const int aw = (base + 3 >= s_) & (base + 3 < e_) ? v.w : 0;
            ssum += (ax + ay) + (az + aw);
            osum += ((ax & 1) + (ay & 1)) + ((az & 1) + (aw & 1));
        }
        // pathological fallback (len > ~1277): per-element predication too
        for (int qi = qa[i] + UNR * 64; (qi << 2) < e_; qi += 64) {
            const int4 v = nt4[qi];
            const int base = qi << 2;
            const int ax = (base + 0 < e_) ? v.x : 0;
            const int ay = (base + 1 < e_) ? v.y : 0;
            const int az = (base + 2 < e_) ? v.z : 0;
            const int aw = (base + 3 < e_) ? v.w : 0;
            ssum += (ax + ay) + (az + aw);
            osum += ((ax & 1) + (ay & 1)) + ((az & 1) + (aw & 1));
        }
        const int shift = i ? 32 : 0;
        pk += ((unsigned long long)(unsigned)ssum << shift)
            | ((unsigned long long)(unsigned)osum << (shift + 16));
    }

    // ---- single packed wave-reduce (6 levels, one u64 chain) ----
    #pragma unroll
    for (int off = 32; off; off >>= 1) pk += __shfl_xor(pk, off);

    // ---- both MLPs concurrently (graph = lane>=32 half) ----
    const bool hb = (lane >= 32);
    const int sT  = hb ? (int)((pk >> 32) & 0xFFFFull) : (int)(pk & 0xFFFFull);
    const int oT  = hb ? (int)((pk >> 48) & 0xFFFFull) : (int)((pk >> 16) & 0xFFFFull);
    const int len = hb ? (sC - sB)                     : (sB - sA);

    const int c1t = oT;                 // count(v==1)
    const int c2t = (sT - oT) >> 1;     // count(v==2)

    const float f0 = (float)(len - c1t - c2t) - 54.5f;
    const float f1 = (float)c1t;
    const float f2 = (float)c2t;
    const float f3 = (float)len - 56.5f;

    // layer 1: unit j on lane&31, per half
    const int j = lane & 31;
    float h1 = sb1[j];
    h1 = fmaf(f0, sW1[      j], h1);
    h1 = fmaf(f1, sW1[ 32 + j], h1);
    h1 = fmaf(f2, sW1[ 64 + j], h1);
    h1 = fmaf(f3, sW1[ 96 + j], h1);
    h1 = fmaxf(0.0f, h1);

    // layer 2: h1 through per-wave LDS (same-wave: no barrier needed)
    sh1[w][hb][j] = h1;

    const int m = lane & 15;
    const float4* h4  = (const float4*)&sh1[w][hb][0];
    const float4* wt4 = (const float4*)&sW2T[m * 36];
    float sm = sb2[m];
    #pragma unroll
    for (int k = 0; k < 8; ++k) {
        const float4 a = h4[k];   // broadcast within half
        const float4 b = wt4[k];  // 2-way across halves: free
        sm = fmaf(a.x, b.x, sm);
        sm = fmaf(a.y, b.y, sm);
        sm = fmaf(a.z, b.z, sm);
        sm = fmaf(a.w, b.w, sm);
    }
    const float h2 = fmaxf(0.0f, sm);

    // layer 3: reduce 16 units within the 16-lane group
    float p3 = h2 * sW3[m];
    p3 += __shfl_xor(p3, 8);
    p3 += __shfl_xor(p3, 4);
    p3 += __shfl_xor(p3, 2);
    p3 += __shfl_xor(p3, 1);

    if (lane == 0)  out[g0]     = p3 + sb3v[0];
    if (lane == 32) out[g0 + 1] = p3 + sb3v[0];
}

extern "C" void kernel_launch(void* const* d_in, const int* in_sizes, int n_in,
                              void* d_out, int out_size, void* d_ws, size_t ws_size,
                              hipStream_t stream) {
    // inputs: 0:x(N) 1:batch(N) 2:node_type(N) 3:num_graphs 4:W1 5:b1 6:W2 7:b2 8:W3 9:b3
    const int*   batch = (const int*)d_in[1];
    const int*   ntype = (const int*)d_in[2];
    const float* W1    = (const float*)d_in[4];
    const float* b1    = (const float*)d_in[5];
    const float* W2    = (const float*)d_in[6];
    const float* b2    = (const float*)d_in[7];
    const float* W3    = (const float*)d_in[8];
    const float* b3    = (const float*)d_in[9];
    float*       out   = (float*)d_out;

    const int n = in_sizes[1];          // 16,777,216 nodes
    const int B = out_size;             // 16,384 graphs

    const int blocks = B / GPB;                      // 2048 blocks, 8192 waves
    fused_kernel<<<blocks, 256, 0, stream>>>(
        batch, ntype, W1, b1, W2, b2, W3, b3, out, n, B, n / B);
}

// Round 20
// 24.647 us; speedup vs baseline: 1.1510x; 1.1510x over previous
//
#include <hip/hip_runtime.h>

// StructOnlyClassifier FINAL (= R18, measured best 24.68us; R19's reg-staged
// load phase cost occupancy 72->47% and regressed to 28.4us -> reverted).
//  - block-shared interpolation searches (9 per block, ~4 probes each)
//  - branchless 5-deep unrolled dwordx4 loads, clamped segment-locally
//  - sum/parity counting (v in {0,1,2}: c1=sum(v&1), c2=(sum v - c1)/2)
//  - single packed u64 wave-reduce: (sA,oA,sB,oB) as 4x16-bit fields
//  - dual-half MLP (lane>=32 = graph B), layer-2 via LDS float4 against
//    transposed+padded W2, layer-3 16-lane shfl reduce
// 2048 blocks x 4 waves, GPW=2, VGPR 24, Occupancy ~72%.

constexpr int GPW = 2;     // graphs per wave
constexpr int GPB = 8;     // graphs per block (4 waves)
constexpr int UNR = 5;     // 5*64 quads = 1280 nodes per graph before fallback

__device__ __forceinline__ int interp_lower_bound(
    const int* __restrict__ batch, int n, int stride, int g)
{
    // first idx with batch[idx] >= g. Invariant: lb in [blo, bhi], 4-aligned.
    int blo = 0, bhi = n;
    long long pos = (long long)g * stride - (stride >> 1);
    int it = 0;
    while (bhi - blo > 4) {
        int p;
        if (it < 5) {                         // interpolation phase
            long long pc = pos;
            if (pc < blo) pc = blo;
            if (pc > bhi - 4) pc = bhi - 4;
            p = (int)pc & ~3;
            ++it;
        } else {                              // binary fallback
            p = ((blo + bhi) >> 1) & ~3;
            if (p > bhi - 4) p = bhi - 4;
        }
        const int4 q = *(const int4*)(batch + p);
        if (q.w < g) {
            blo = p + 4;
            pos = p + 4 + (long long)(g - q.w) * stride - (stride >> 1);
        } else if (q.x >= g) {
            bhi = p;
            pos = p + (long long)(g - q.x) * stride - (stride >> 1);
        } else {
            return p + 1 + (q.y < g) + (q.z < g);
        }
    }
    if (bhi > blo) {
        const int4 q = *(const int4*)(batch + blo);
        return blo + (q.x < g) + (q.y < g) + (q.z < g) + (q.w < g);
    }
    return blo;
}

__global__ __launch_bounds__(256) void fused_kernel(
    const int* __restrict__ batch, const int* __restrict__ ntype,
    const float* __restrict__ W1, const float* __restrict__ b1,
    const float* __restrict__ W2, const float* __restrict__ b2,
    const float* __restrict__ W3, const float* __restrict__ b3,
    float* __restrict__ out, int n, int B, int stride)
{
    __shared__ float sW1[128], sb1[32], sb2[16], sW3[16], sb3v[1];
    __shared__ __attribute__((aligned(16))) float sW2T[16 * 36]; // [m][j] pad 36
    __shared__ __attribute__((aligned(16))) float sh1[4][2][32]; // [wave][half][j]
    __shared__ int sS[GPB + 1];

    const int tid = threadIdx.x;
    const int bi  = blockIdx.x;

    // ---- weight staging (issue loads first) ----
    if (tid < 128) sW1[tid] = W1[tid];
    for (int i = tid; i < 512; i += 256) {            // transpose W2 (32,16)
        const int j = i >> 4, m = i & 15;
        sW2T[m * 36 + j] = W2[i];
    }
    if      (tid < 32)  sb1[tid]      = b1[tid];
    else if (tid < 48)  sb2[tid - 32] = b2[tid - 32];
    else if (tid < 64)  sW3[tid - 48] = W3[tid - 48];
    else if (tid == 64) sb3v[0]       = b3[0];

    // ---- block-shared boundary searches: 9 per block ----
    if (tid <= GPB) {
        const int g = bi * GPB + tid;                 // <= B by construction
        sS[tid] = interp_lower_bound(batch, n, stride, g);
    }
    __syncthreads();

    const int w    = tid >> 6;
    const int lane = tid & 63;
    const int g0   = bi * GPB + w * GPW;

    const int s0  = sS[w * GPW];
    const int s1  = sS[w * GPW + 1];
    const int s2b = sS[w * GPW + 2];

    // ---- phase 1: stream counts, packed (sA,oA,sB,oB) 4x16-bit in one u64 ----
    const int4* nt4 = (const int4*)ntype;
    unsigned long long pk = 0ull;    // [0:16)=sA [16:32)=oA [32:48)=sB [48:64)=oB

    #pragma unroll
    for (int i = 0; i < 2; ++i) {
        const int s = (i == 0) ? s0 : s1;
        const int e = (i == 0) ? s1 : s2b;
        const int shift = i ? 32 : 0;
        int sa = (s + 3) & ~3; if (sa > e) sa = e;
        int ea = e & ~3;       if (ea < sa) ea = sa;

        int ssum = 0, osum = 0;
        {   // head scalars [s, sa): <=3 active lanes
            const int idx = s + lane;
            if (idx < sa) { const int v = ntype[idx]; ssum += v; osum += v & 1; }
        }
        const int qa    = (sa >> 2) + lane;
        const int qe    = (ea >> 2);
        const int qlast = max(qe - 1, 0);     // segment-local clamp target
        #pragma unroll
        for (int u = 0; u < UNR; ++u) {       // branchless: all loads batch-issue
            const int qi = qa + u * 64;
            const int4 v = nt4[min(qi, qlast)];   // inactive -> own last quad (L1)
            if (qi < qe) {                        // per-lane predication (cndmask)
                ssum += (v.x + v.y) + (v.z + v.w);
                osum += ((v.x & 1) + (v.y & 1)) + ((v.z & 1) + (v.w & 1));
            }
        }
        for (int qi = qa + UNR * 64; qi < qe; qi += 64) {  // pathological fallback
            const int4 v = nt4[qi];
            ssum += (v.x + v.y) + (v.z + v.w);
            osum += ((v.x & 1) + (v.y & 1)) + ((v.z & 1) + (v.w & 1));
        }
        {   // tail scalars [ea, e): <=3 active lanes
            const int idx = ea + lane;
            if (idx < e) { const int v = ntype[idx]; ssum += v; osum += v & 1; }
        }
        pk += ((unsigned long long)(unsigned)ssum << shift)
            | ((unsigned long long)(unsigned)osum << (shift + 16));
    }

    // ---- single packed wave-reduce (6 levels, one u64 chain) ----
    #pragma unroll
    for (int off = 32; off; off >>= 1) pk += __shfl_xor(pk, off);

    // ---- phase 2: both MLPs concurrently (graph = lane>=32 half) ----
    const bool hb = (lane >= 32);
    const int sT  = hb ? (int)((pk >> 32) & 0xFFFFull) : (int)(pk & 0xFFFFull);
    const int oT  = hb ? (int)((pk >> 48) & 0xFFFFull) : (int)((pk >> 16) & 0xFFFFull);
    const int len = hb ? (s2b - s1)                    : (s1 - s0);

    const int c1t = oT;                 // count(v==1)
    const int c2t = (sT - oT) >> 1;     // count(v==2)

    const float f0 = (float)(len - c1t - c2t) - 54.5f;
    const float f1 = (float)c1t;
    const float f2 = (float)c2t;
    const float f3 = (float)len - 56.5f;

    // layer 1: unit j on lane&31, per half
    const int j = lane & 31;
    float h1 = sb1[j];
    h1 = fmaf(f0, sW1[      j], h1);
    h1 = fmaf(f1, sW1[ 32 + j], h1);
    h1 = fmaf(f2, sW1[ 64 + j], h1);
    h1 = fmaf(f3, sW1[ 96 + j], h1);
    h1 = fmaxf(0.0f, h1);

    // layer 2: h1 through per-wave LDS (same-wave: no barrier needed)
    sh1[w][hb][j] = h1;

    const int m = lane & 15;
    const float4* h4  = (const float4*)&sh1[w][hb][0];
    const float4* wt4 = (const float4*)&sW2T[m * 36];
    float sm = sb2[m];
    #pragma unroll
    for (int k = 0; k < 8; ++k) {
        const float4 a = h4[k];   // broadcast within half
        const float4 b = wt4[k];  // 2-way across halves: free
        sm = fmaf(a.x, b.x, sm);
        sm = fmaf(a.y, b.y, sm);
        sm = fmaf(a.z, b.z, sm);
        sm = fmaf(a.w, b.w, sm);
    }
    const float h2 = fmaxf(0.0f, sm);

    // layer 3: reduce 16 units within the 16-lane group
    float p3 = h2 * sW3[m];
    p3 += __shfl_xor(p3, 8);
    p3 += __shfl_xor(p3, 4);
    p3 += __shfl_xor(p3, 2);
    p3 += __shfl_xor(p3, 1);

    if (lane == 0)  out[g0]     = p3 + sb3v[0];
    if (lane == 32) out[g0 + 1] = p3 + sb3v[0];
}

extern "C" void kernel_launch(void* const* d_in, const int* in_sizes, int n_in,
                              void* d_out, int out_size, void* d_ws, size_t ws_size,
                              hipStream_t stream) {
    // inputs: 0:x(N) 1:batch(N) 2:node_type(N) 3:num_graphs 4:W1 5:b1 6:W2 7:b2 8:W3 9:b3
    const int*   batch = (const int*)d_in[1];
    const int*   ntype = (const int*)d_in[2];
    const float* W1    = (const float*)d_in[4];
    const float* b1    = (const float*)d_in[5];
    const float* W2    = (const float*)d_in[6];
    const float* b2    = (const float*)d_in[7];
    const float* W3    = (const float*)d_in[8];
    const float* b3    = (const float*)d_in[9];
    float*       out   = (float*)d_out;

    const int n = in_sizes[1];          // 16,777,216 nodes
    const int B = out_size;             // 16,384 graphs

    const int blocks = B / GPB;                      // 2048 blocks, 8192 waves
    fused_kernel<<<blocks, 256, 0, stream>>>(
        batch, ntype, W1, b1, W2, b2, W3, b3, out, n, B, n / B);
}